// Round 4
// baseline (586.899 us; speedup 1.0000x reference)
//
#include <hip/hip_runtime.h>
#include <math.h>

typedef int    intx8    __attribute__((ext_vector_type(8)));   // 8 dwords = 32 fp8
typedef float  floatx16 __attribute__((ext_vector_type(16)));  // MFMA 32x32 C/D

#define N_ROWS 8192
#define H_DIM  1024
#define V_DIM  32000
#define IGNORE_INDEX (-100)

#define S_SPLITS 25          // V split into 25 chunks of 10 col-tiles (1280 cols)
#define TILES_PER_SPLIT 10
#define BM 128
#define BN 128
#define BK 64                // one K-step = one mfma_scale_32x32x64 K

#define LOG2E 1.4426950408889634f
#define LN2   0.6931471805599453f

// fp32 [R][1024] row-major -> fp8 e4m3 (value*scale), "unit-transposed"
// [H/16 k-units][R][16B]. Direct (no LDS): one thread per (u, r).
// Read: 64B contiguous per lane (full cache lines). Write: 16B/lane, coalesced 1KB/wave.
__global__ __launch_bounds__(256) void convert_fp8(const float* __restrict__ in,
                                                   unsigned char* __restrict__ out,
                                                   int R, float scale) {
  const int r = blockIdx.x * 256 + threadIdx.x;
  const int u = blockIdx.y;                  // k-unit 0..63
  const float4* src = (const float4*)(in + (size_t)r * H_DIM + u * 16);
  uint4 res;
#pragma unroll
  for (int j = 0; j < 4; ++j) {
    const float4 v = src[j];
    int p = __builtin_amdgcn_cvt_pk_fp8_f32(v.x * scale, v.y * scale, 0, false);
    p = __builtin_amdgcn_cvt_pk_fp8_f32(v.z * scale, v.w * scale, p, true);
    ((int*)&res)[j] = p;
  }
  *(uint4*)(out + ((size_t)u * R + r) * 16) = res;
}

// Fused GEMM + sumexp. fp8 e4m3, x pre-scaled by log2e (base-2 softmax domain).
// mfma_scale_f32_32x32x64_f8f6f4 with unity scales (0x7F = E8M0 2^0).
// launch_bounds(256,3): cap unified VGPR+AGPR at 170 -> 3 blocks/CU (was 2 at bound=2,
// where the allocator used ~200 unified regs; m132 measured 2 vs 3 blocks/CU as 1.7x).
__global__ __launch_bounds__(256, 3) void flce_main(const unsigned char* __restrict__ xs,
                                                    const unsigned char* __restrict__ wsb,
                                                    const float* __restrict__ bias,
                                                    float* __restrict__ partials) {
  __shared__ __align__(16) unsigned char smA[4 * 128 * 16];  // [u 0..3][row 0..127][16B] = 8KB
  __shared__ __align__(16) unsigned char smB[4 * 128 * 16];

  const int tid  = threadIdx.x;
  const int lane = tid & 63;
  const int w    = tid >> 6;      // wave 0..3
  const int l31  = lane & 31;
  const int half = lane >> 5;     // k-half within instruction (32 k each)
  const int wm   = w >> 1;        // 64-row half of tile
  const int wn   = w & 1;         // 64-col half
  const int row0 = blockIdx.x * BM;
  const int sidx = blockIdx.y;

  const int rbA = (wm * 64 + l31) * 16;   // + mb*512 per 32-row frag
  const int rbB = (wn * 64 + l31) * 16;
  const int uo  = half * 4096;            // units {0,1} vs {2,3} (2 x 2048B)

  float l_state[32];                      // slot = mb*16 + reg; per-lane Σ 2^v over its cols
#pragma unroll
  for (int i = 0; i < 32; ++i) l_state[i] = 0.f;

#pragma unroll 1
  for (int ct = 0; ct < TILES_PER_SPLIT; ++ct) {
    const int n0 = (sidx * TILES_PER_SPLIT + ct) * BN;
    floatx16 acc[2][2];
#pragma unroll
    for (int mb = 0; mb < 2; ++mb)
#pragma unroll
      for (int nb = 0; nb < 2; ++nb)
#pragma unroll
        for (int i = 0; i < 16; ++i) acc[mb][nb][i] = 0.f;

#pragma unroll 1
    for (int k0i = 0; k0i < H_DIM / BK; ++k0i) {   // 16 steps of K=64 (4 k-units)
      const int ub = k0i * 4;
      __syncthreads();                             // prev reads done before overwrite
#pragma unroll
      for (int j = 0; j < 2; ++j) {                // 16 wave-DMAs total (8 A + 8 B, 1KB each)
        const int s = j * 4 + w;
        const int u = s >> 1;
        const int rh = s & 1;
        __builtin_amdgcn_global_load_lds(
            (const __attribute__((address_space(1))) void*)(xs + ((size_t)(ub + u) * N_ROWS + row0 + rh * 64 + lane) * 16),
            (__attribute__((address_space(3))) void*)(smA + s * 1024 + lane * 16),
            16, 0, 0);
        __builtin_amdgcn_global_load_lds(
            (const __attribute__((address_space(1))) void*)(wsb + ((size_t)(ub + u) * V_DIM + n0 + rh * 64 + lane) * 16),
            (__attribute__((address_space(3))) void*)(smB + s * 1024 + lane * 16),
            16, 0, 0);
      }
      __syncthreads();                             // drain DMA before ds_read

      union { intx8 v; uint4 q[2]; } a[2], b[2];
#pragma unroll
      for (int mb = 0; mb < 2; ++mb) {             // lane's 32B of A: units 2*half, 2*half+1
        a[mb].q[0] = *(const uint4*)(smA + uo + mb * 512 + rbA);
        a[mb].q[1] = *(const uint4*)(smA + uo + 2048 + mb * 512 + rbA);
      }
#pragma unroll
      for (int nb = 0; nb < 2; ++nb) {
        b[nb].q[0] = *(const uint4*)(smB + uo + nb * 512 + rbB);
        b[nb].q[1] = *(const uint4*)(smB + uo + 2048 + nb * 512 + rbB);
      }
#pragma unroll
      for (int mb = 0; mb < 2; ++mb)
#pragma unroll
        for (int nb = 0; nb < 2; ++nb)
          acc[mb][nb] = __builtin_amdgcn_mfma_scale_f32_32x32x64_f8f6f4(
              a[mb].v, b[nb].v, acc[mb][nb],
              0, 0,                      // cbsz/blgp: fp8 e4m3 A and B
              0, 0x7F7F7F7F,             // scale A = 1.0
              0, 0x7F7F7F7F);            // scale B = 1.0
    }

    // Epilogue: Σ 2^(acc + bias*log2e). C/D 32x32 layout [m74/m101]:
    // col = nb*32 + l31 (+wn*64), row = mb*32 + 4*half + (r&3) + 8*(r>>2) (+wm*64).
    const float b0 = bias[n0 + wn * 64 + l31] * LOG2E;
    const float b1 = bias[n0 + wn * 64 + 32 + l31] * LOG2E;
#pragma unroll
    for (int mb = 0; mb < 2; ++mb)
#pragma unroll
      for (int r = 0; r < 16; ++r)
        l_state[mb * 16 + r] += exp2f(acc[mb][0][r] + b0) + exp2f(acc[mb][1][r] + b1);
  }

  // Reduce over this wave's 64 cols: butterfly within the 32-lane half.
#pragma unroll
  for (int s = 0; s < 32; ++s) {
    float v = l_state[s];
#pragma unroll
    for (int off = 1; off < 32; off <<= 1) v += __shfl_xor(v, off, 64);
    l_state[s] = v;
  }

  // Combine wn=0/1 halves per row via LDS, write per-(row,split) partial sum.
  __syncthreads();
  float* comb = (float*)smA;
  if (wn == 0 && l31 == 0) {
#pragma unroll
    for (int s = 0; s < 32; ++s) {
      const int mb = s >> 4, r = s & 15;
      const int row = wm * 64 + mb * 32 + 4 * half + (r & 3) + 8 * (r >> 2);
      comb[row] = l_state[s];
    }
  }
  __syncthreads();
  if (wn == 1 && l31 == 0) {
#pragma unroll
    for (int s = 0; s < 32; ++s) {
      const int mb = s >> 4, r = s & 15;
      const int row = wm * 64 + mb * 32 + 4 * half + (r & 3) + 8 * (r >> 2);
      partials[(size_t)(row0 + row) * S_SPLITS + sidx] = comb[row] + l_state[s];
    }
  }
}

// Exact fp32 target logit: one wave per row.
__global__ __launch_bounds__(256) void tgt_kernel(const float* __restrict__ x,
                                                  const float* __restrict__ wgt,
                                                  const float* __restrict__ bias,
                                                  const int* __restrict__ target,
                                                  float* __restrict__ tgt_logit) {
  const int r = blockIdx.x * 4 + (threadIdx.x >> 6);
  const int lane = threadIdx.x & 63;
  const int t = target[r];
  const int tt = (t == IGNORE_INDEX) ? 0 : t;
  const float4* xr = (const float4*)(x + (size_t)r * H_DIM);
  const float4* wr = (const float4*)(wgt + (size_t)tt * H_DIM);
  float acc = 0.f;
#pragma unroll
  for (int i = 0; i < 4; ++i) {
    const float4 a = xr[lane + i * 64];
    const float4 b = wr[lane + i * 64];
    acc += a.x * b.x + a.y * b.y + a.z * b.z + a.w * b.w;
  }
#pragma unroll
  for (int off = 32; off >= 1; off >>= 1) acc += __shfl_xor(acc, off, 64);
  if (lane == 0) tgt_logit[r] = acc + bias[tt];
}

// Per-row loss + per-block partial sums. partials hold Σ2^v per (row, split):
// lse_nat = ln2 * log2(Σ_s l_s).
__global__ __launch_bounds__(256) void loss_rows(const float* __restrict__ partials,
                                                 const float* __restrict__ tgt_logit,
                                                 const int* __restrict__ target,
                                                 float* __restrict__ bsums) {
  const int r = blockIdx.x * 256 + threadIdx.x;
  float l = 0.f;
#pragma unroll
  for (int s = 0; s < S_SPLITS; ++s) l += partials[(size_t)r * S_SPLITS + s];
  const float lse = LN2 * __log2f(l);
  const bool valid = (target[r] != IGNORE_INDEX);
  float loss = valid ? (lse - tgt_logit[r]) : 0.f;
  float cnt  = valid ? 1.f : 0.f;
  const int lane = threadIdx.x & 63;
  const int w = threadIdx.x >> 6;
#pragma unroll
  for (int off = 32; off >= 1; off >>= 1) {
    loss += __shfl_xor(loss, off, 64);
    cnt  += __shfl_xor(cnt, off, 64);
  }
  __shared__ float sl[4], sc[4];
  if (lane == 0) { sl[w] = loss; sc[w] = cnt; }
  __syncthreads();
  if (threadIdx.x == 0) {
    float S = 0.f, C = 0.f;
    for (int i = 0; i < 4; ++i) { S += sl[i]; C += sc[i]; }
    bsums[blockIdx.x] = S;
    bsums[32 + blockIdx.x] = C;
  }
}

__global__ void finalize(const float* __restrict__ bsums, float* __restrict__ out) {
  const int t = threadIdx.x;  // 64 threads
  float s = (t < 32) ? bsums[t] : 0.f;
  float c = (t < 32) ? bsums[32 + t] : 0.f;
#pragma unroll
  for (int off = 32; off >= 1; off >>= 1) {
    s += __shfl_xor(s, off, 64);
    c += __shfl_xor(c, off, 64);
  }
  if (t == 0) out[0] = s / fmaxf(c, 1.f);
}

extern "C" void kernel_launch(void* const* d_in, const int* in_sizes, int n_in,
                              void* d_out, int out_size, void* d_ws, size_t ws_size,
                              hipStream_t stream) {
  const float* x    = (const float*)d_in[0];
  const float* wgt  = (const float*)d_in[1];
  const float* bias = (const float*)d_in[2];
  const int*   tgt  = (const int*)d_in[3];
  float* out = (float*)d_out;

  char* ws = (char*)d_ws;
  const size_t XS8 = (size_t)N_ROWS * H_DIM;        // 8 MB fp8 x (pre-scaled by log2e)
  const size_t WS8 = (size_t)V_DIM * H_DIM;         // 32.8 MB fp8 W
  const size_t PB  = (size_t)N_ROWS * S_SPLITS * 4; // per-(row,split) sumexp
  unsigned char* xs8 = (unsigned char*)ws;
  unsigned char* ws8 = (unsigned char*)(ws + XS8);
  float* partials = (float*)(ws + XS8 + WS8);
  float* tgt_lg   = (float*)(ws + XS8 + WS8 + PB);
  float* bsums    = (float*)(ws + XS8 + WS8 + PB + (size_t)N_ROWS * 4);

  convert_fp8<<<dim3(N_ROWS / 256, H_DIM / 16), 256, 0, stream>>>(x, xs8, N_ROWS, LOG2E);
  convert_fp8<<<dim3(V_DIM / 256, H_DIM / 16), 256, 0, stream>>>(wgt, ws8, V_DIM, 1.0f);
  tgt_kernel<<<N_ROWS / 4, 256, 0, stream>>>(x, wgt, bias, tgt, tgt_lg);
  flce_main<<<dim3(N_ROWS / BM, S_SPLITS), 256, 0, stream>>>(xs8, ws8, bias, partials);
  loss_rows<<<N_ROWS / 256, 256, 0, stream>>>(partials, tgt_lg, tgt, bsums);
  finalize<<<1, 64, 0, stream>>>(bsums, out);
}

// Round 5
// 495.932 us; speedup vs baseline: 1.1834x; 1.1834x over previous
//
#include <hip/hip_runtime.h>
#include <math.h>

typedef int    intx8    __attribute__((ext_vector_type(8)));   // 8 dwords = 32 fp8
typedef float  floatx16 __attribute__((ext_vector_type(16)));  // MFMA 32x32 C/D

#define N_ROWS 8192
#define H_DIM  1024
#define V_DIM  32000
#define V_PAD  32768         // padded V: pad cols killed via bias = -1e30
#define IGNORE_INDEX (-100)

#define S_SPLITS 16          // 16 splits x 16 tiles x 128 cols = 32768
#define TILES_PER_SPLIT 16
#define BM 256
#define BN 128
#define BK 128               // 8 k-units of 16B; 2 MFMA-K (64) per step

#define LOG2E 1.4426950408889634f
#define LN2   0.6931471805599453f

// fp32 [R][1024] row-major -> fp8 e4m3 (value*scale), "unit-transposed"
// [64 k-units][Rstride][16B]. One thread per (u, r): 64B contiguous read, 16B coalesced write.
__global__ __launch_bounds__(256) void convert_fp8(const float* __restrict__ in,
                                                   unsigned char* __restrict__ out,
                                                   int Rstride, float scale) {
  const int r = blockIdx.x * 256 + threadIdx.x;
  const int u = blockIdx.y;                  // k-unit 0..63
  const float4* src = (const float4*)(in + (size_t)r * H_DIM + u * 16);
  uint4 res;
#pragma unroll
  for (int j = 0; j < 4; ++j) {
    const float4 v = src[j];
    int p = __builtin_amdgcn_cvt_pk_fp8_f32(v.x * scale, v.y * scale, 0, false);
    p = __builtin_amdgcn_cvt_pk_fp8_f32(v.z * scale, v.w * scale, p, true);
    ((int*)&res)[j] = p;
  }
  *(uint4*)(out + ((size_t)u * Rstride + r) * 16) = res;
}

// Padded bias, pre-scaled to base-2 domain. Pad cols get -1e30 -> exp2 -> 0
// (poisoned pad weights give finite acc; -1e30 dominates).
__global__ __launch_bounds__(256) void pad_bias(const float* __restrict__ bias,
                                                float* __restrict__ biasp) {
  const int i = blockIdx.x * 256 + threadIdx.x;
  biasp[i] = (i < V_DIM) ? bias[i] * LOG2E : -1e30f;
}

// Fused GEMM + sumexp. fp8 e4m3, x pre-scaled by log2e (base-2 softmax domain).
// mfma_scale_f32_32x32x64_f8f6f4, unity scales (0x7F = E8M0 2^0).
// BM=256: wave w owns rows [w*64, w*64+64) x all 128 cols -> acc[2][4] (128 AGPR),
// 16 MFMA per barrier-pair per wave (4x the round-3 amortization of the ~1000cyc drain).
// Grid 32x16 = 512 blocks = exactly 2/CU: one clean residency round, no tail.
__global__ __launch_bounds__(256, 2) void flce_main(const unsigned char* __restrict__ xs,
                                                    const unsigned char* __restrict__ wsb,
                                                    const float* __restrict__ biasp,
                                                    float* __restrict__ partials) {
  __shared__ __align__(16) unsigned char smA[8 * 256 * 16];  // 32KB [u][row][16B]
  __shared__ __align__(16) unsigned char smB[8 * 128 * 16];  // 16KB

  const int tid  = threadIdx.x;
  const int lane = tid & 63;
  const int w    = tid >> 6;      // wave 0..3: rows [w*64, w*64+64)
  const int l31  = lane & 31;
  const int half = lane >> 5;     // k-half within MFMA (32 k each)
  const int wr   = w * 64;
  const int row0 = blockIdx.x * BM;
  const int sidx = blockIdx.y;

  float l_state[32];              // slot = mb*16 + reg; per-lane Σ 2^v over its cols
#pragma unroll
  for (int i = 0; i < 32; ++i) l_state[i] = 0.f;

#pragma unroll 1
  for (int ct = 0; ct < TILES_PER_SPLIT; ++ct) {
    const int n0 = (sidx * TILES_PER_SPLIT + ct) * BN;
    floatx16 acc[2][4];
#pragma unroll
    for (int mb = 0; mb < 2; ++mb)
#pragma unroll
      for (int nb = 0; nb < 4; ++nb)
#pragma unroll
        for (int i = 0; i < 16; ++i) acc[mb][nb][i] = 0.f;

#pragma unroll 1
    for (int k0i = 0; k0i < H_DIM / BK; ++k0i) {   // 8 steps of BK=128 (8 k-units)
      const int ub = k0i * 8;
      __syncthreads();                             // prev reads done before overwrite
      // A: 32 chunks (8 u x 4 row-blocks of 64), one 1KB DMA each; c = j*4+w covers all.
#pragma unroll
      for (int j = 0; j < 8; ++j) {
        const int c = j * 4 + w;
        const int u = c >> 2;
        const int rb = c & 3;
        __builtin_amdgcn_global_load_lds(
            (const __attribute__((address_space(1))) void*)(xs + ((size_t)(ub + u) * N_ROWS + row0 + rb * 64 + lane) * 16),
            (__attribute__((address_space(3))) void*)(smA + ((u * 256 + rb * 64 + lane) * 16)),
            16, 0, 0);
      }
      // B: 16 chunks (8 u x 2 row-blocks of 64).
#pragma unroll
      for (int j = 0; j < 4; ++j) {
        const int c = j * 4 + w;
        const int u = c >> 1;
        const int rb = c & 1;
        __builtin_amdgcn_global_load_lds(
            (const __attribute__((address_space(1))) void*)(wsb + ((size_t)(ub + u) * V_PAD + n0 + rb * 64 + lane) * 16),
            (__attribute__((address_space(3))) void*)(smB + ((u * 128 + rb * 64 + lane) * 16)),
            16, 0, 0);
      }
      __syncthreads();                             // drain DMA before ds_read

#pragma unroll
      for (int s2 = 0; s2 < 2; ++s2) {             // two K=64 MFMA sub-steps
        const int ua = s2 * 4 + half * 2;          // this lane-half's 2 units
        union { intx8 v; uint4 q[2]; } a[2], b[4];
#pragma unroll
        for (int mb = 0; mb < 2; ++mb) {
          a[mb].q[0] = *(const uint4*)(smA + ((ua * 256 + wr + mb * 32 + l31) * 16));
          a[mb].q[1] = *(const uint4*)(smA + (((ua + 1) * 256 + wr + mb * 32 + l31) * 16));
        }
#pragma unroll
        for (int nb = 0; nb < 4; ++nb) {
          b[nb].q[0] = *(const uint4*)(smB + ((ua * 128 + nb * 32 + l31) * 16));
          b[nb].q[1] = *(const uint4*)(smB + (((ua + 1) * 128 + nb * 32 + l31) * 16));
        }
#pragma unroll
        for (int mb = 0; mb < 2; ++mb)
#pragma unroll
          for (int nb = 0; nb < 4; ++nb)
            acc[mb][nb] = __builtin_amdgcn_mfma_scale_f32_32x32x64_f8f6f4(
                a[mb].v, b[nb].v, acc[mb][nb],
                0, 0,                      // fp8 e4m3 A and B
                0, 0x7F7F7F7F,             // scale A = 1.0
                0, 0x7F7F7F7F);            // scale B = 1.0
      }
    }

    // Epilogue: Σ 2^(acc + bias2). C/D 32x32 layout [m74/m101]:
    // col = nb*32 + l31, row = wr + mb*32 + 4*half + (r&3) + 8*(r>>2).
    float bnb[4];
#pragma unroll
    for (int nb = 0; nb < 4; ++nb) bnb[nb] = biasp[n0 + nb * 32 + l31];
#pragma unroll
    for (int mb = 0; mb < 2; ++mb)
#pragma unroll
      for (int r = 0; r < 16; ++r) {
        float s = exp2f(acc[mb][0][r] + bnb[0]) + exp2f(acc[mb][1][r] + bnb[1])
                + exp2f(acc[mb][2][r] + bnb[2]) + exp2f(acc[mb][3][r] + bnb[3]);
        l_state[mb * 16 + r] += s;
      }
  }

  // Sum over this wave's 128 cols: butterfly within the 32-lane half (rows differ per half).
#pragma unroll
  for (int s = 0; s < 32; ++s) {
    float v = l_state[s];
#pragma unroll
    for (int off = 1; off < 32; off <<= 1) v += __shfl_xor(v, off, 64);
    l_state[s] = v;
  }

  // Each wave owns all cols of its 64 rows -> direct write, no cross-wave combine.
  if (l31 == 0) {
#pragma unroll
    for (int s = 0; s < 32; ++s) {
      const int mb = s >> 4, r = s & 15;
      const int row = wr + mb * 32 + 4 * half + (r & 3) + 8 * (r >> 2);
      partials[(size_t)(row0 + row) * S_SPLITS + sidx] = l_state[s];
    }
  }
}

// Exact fp32 target logit: one wave per row.
__global__ __launch_bounds__(256) void tgt_kernel(const float* __restrict__ x,
                                                  const float* __restrict__ wgt,
                                                  const float* __restrict__ bias,
                                                  const int* __restrict__ target,
                                                  float* __restrict__ tgt_logit) {
  const int r = blockIdx.x * 4 + (threadIdx.x >> 6);
  const int lane = threadIdx.x & 63;
  const int t = target[r];
  const int tt = (t == IGNORE_INDEX) ? 0 : t;
  const float4* xr = (const float4*)(x + (size_t)r * H_DIM);
  const float4* wr = (const float4*)(wgt + (size_t)tt * H_DIM);
  float acc = 0.f;
#pragma unroll
  for (int i = 0; i < 4; ++i) {
    const float4 a = xr[lane + i * 64];
    const float4 b = wr[lane + i * 64];
    acc += a.x * b.x + a.y * b.y + a.z * b.z + a.w * b.w;
  }
#pragma unroll
  for (int off = 32; off >= 1; off >>= 1) acc += __shfl_xor(acc, off, 64);
  if (lane == 0) tgt_logit[r] = acc + bias[tt];
}

// Per-row loss + per-block partial sums. partials hold Σ2^v per (row, split):
// lse_nat = ln2 * log2(Σ_s l_s).
__global__ __launch_bounds__(256) void loss_rows(const float* __restrict__ partials,
                                                 const float* __restrict__ tgt_logit,
                                                 const int* __restrict__ target,
                                                 float* __restrict__ bsums) {
  const int r = blockIdx.x * 256 + threadIdx.x;
  float l = 0.f;
#pragma unroll
  for (int s = 0; s < S_SPLITS; ++s) l += partials[(size_t)r * S_SPLITS + s];
  const float lse = LN2 * __log2f(l);
  const bool valid = (target[r] != IGNORE_INDEX);
  float loss = valid ? (lse - tgt_logit[r]) : 0.f;
  float cnt  = valid ? 1.f : 0.f;
  const int lane = threadIdx.x & 63;
  const int w = threadIdx.x >> 6;
#pragma unroll
  for (int off = 32; off >= 1; off >>= 1) {
    loss += __shfl_xor(loss, off, 64);
    cnt  += __shfl_xor(cnt, off, 64);
  }
  __shared__ float sl[4], sc[4];
  if (lane == 0) { sl[w] = loss; sc[w] = cnt; }
  __syncthreads();
  if (threadIdx.x == 0) {
    float S = 0.f, C = 0.f;
    for (int i = 0; i < 4; ++i) { S += sl[i]; C += sc[i]; }
    bsums[blockIdx.x] = S;
    bsums[32 + blockIdx.x] = C;
  }
}

__global__ void finalize(const float* __restrict__ bsums, float* __restrict__ out) {
  const int t = threadIdx.x;  // 64 threads
  float s = (t < 32) ? bsums[t] : 0.f;
  float c = (t < 32) ? bsums[32 + t] : 0.f;
#pragma unroll
  for (int off = 32; off >= 1; off >>= 1) {
    s += __shfl_xor(s, off, 64);
    c += __shfl_xor(c, off, 64);
  }
  if (t == 0) out[0] = s / fmaxf(c, 1.f);
}

extern "C" void kernel_launch(void* const* d_in, const int* in_sizes, int n_in,
                              void* d_out, int out_size, void* d_ws, size_t ws_size,
                              hipStream_t stream) {
  const float* x    = (const float*)d_in[0];
  const float* wgt  = (const float*)d_in[1];
  const float* bias = (const float*)d_in[2];
  const int*   tgt  = (const int*)d_in[3];
  float* out = (float*)d_out;

  char* ws = (char*)d_ws;
  const size_t XS8 = (size_t)N_ROWS * H_DIM;        // 8 MB fp8 x (pre-scaled by log2e)
  const size_t WS8 = (size_t)V_PAD * H_DIM;         // 33.5 MB fp8 W (rows >= V_DIM stay poisoned)
  const size_t BP  = (size_t)V_PAD * 4;             // padded bias (base-2 domain)
  const size_t PB  = (size_t)N_ROWS * S_SPLITS * 4; // per-(row,split) sumexp
  unsigned char* xs8 = (unsigned char*)ws;
  unsigned char* ws8 = (unsigned char*)(ws + XS8);
  float* biasp    = (float*)(ws + XS8 + WS8);
  float* partials = (float*)(ws + XS8 + WS8 + BP);
  float* tgt_lg   = (float*)(ws + XS8 + WS8 + BP + PB);
  float* bsums    = (float*)(ws + XS8 + WS8 + BP + PB + (size_t)N_ROWS * 4);

  convert_fp8<<<dim3(N_ROWS / 256, H_DIM / 16), 256, 0, stream>>>(x, xs8, N_ROWS, LOG2E);
  convert_fp8<<<dim3(V_DIM / 256, H_DIM / 16), 256, 0, stream>>>(wgt, ws8, V_PAD, 1.0f);
  pad_bias<<<V_PAD / 256, 256, 0, stream>>>(bias, biasp);
  tgt_kernel<<<N_ROWS / 4, 256, 0, stream>>>(x, wgt, bias, tgt, tgt_lg);
  flce_main<<<dim3(N_ROWS / BM, S_SPLITS), 256, 0, stream>>>(xs8, ws8, biasp, partials);
  loss_rows<<<N_ROWS / 256, 256, 0, stream>>>(partials, tgt_lg, tgt, bsums);
  finalize<<<1, 64, 0, stream>>>(bsums, out);
}